// Round 1
// baseline (1535.517 us; speedup 1.0000x reference)
//
#include <hip/hip_runtime.h>
#include <cstdint>
#include <cstddef>

// ---------------------------------------------------------------------------
// MambaDecoderLayer: rmsnorm1 -> in_proj -> (dt GEMM + softplus) -> scan
//                    -> out_proj (+resid) -> rmsnorm2 -> gate/up GEMM
//                    -> silu*mul -> down GEMM (+resid)
// All GEMMs: C[m,n] = sum_k A[m,k] * W[n,k]  (A MxK row-major fp32,
// W NxK row-major fp32), bf16 MFMA 16x16x32, fp32 accum.
// ---------------------------------------------------------------------------

#define L_SEQ   1024
#define DMODEL  2048
#define DINNER  4096
#define DXB     1024
#define DSTATE  16
#define DTRANK  128
#define INTER   8192
#define ZROW    10368   // 2*DINNER + 2*DXB + DTRANK

typedef __attribute__((ext_vector_type(8))) short  short8;
typedef __attribute__((ext_vector_type(4))) float  floatx4;

__device__ __forceinline__ unsigned short f2bf(float f) {
  unsigned u = __float_as_uint(f);
  u += 0x7FFFu + ((u >> 16) & 1u);     // round-to-nearest-even
  return (unsigned short)(u >> 16);
}

__device__ __forceinline__ void st_bf4(unsigned short* p, float4 v) {
  ushort4 o;
  o.x = f2bf(v.x); o.y = f2bf(v.y); o.z = f2bf(v.z); o.w = f2bf(v.w);
  *(ushort4*)p = o;
}

// ---------------------------------------------------------------------------
// GEMM: 128x128 tile, BK=32, 256 threads (4 waves as 2x2 of 64x64).
// EPI: 0 = none, 1 = softplus(acc + bias[col]), 2 = acc + resid[row,col]
// ---------------------------------------------------------------------------
template <int EPI>
__global__ void __launch_bounds__(256) gemm_bt(
    const float* __restrict__ A, int lda,
    const float* __restrict__ W,            // N x K, ld = K
    float* __restrict__ C, int ldc, int K,
    const float* __restrict__ aux)
{
  __shared__ alignas(16) unsigned short As[128 * 40];  // +8 bf16 pad: 2-way max
  __shared__ alignas(16) unsigned short Bs[128 * 40];

  const int m0 = blockIdx.y * 128;
  const int n0 = blockIdx.x * 128;
  const int t    = threadIdx.x;
  const int r    = t >> 1;        // 0..127  staging row
  const int half = t & 1;         // 0/1     staging k-half (16 floats each)
  const int lane = t & 63;
  const int wave = t >> 6;
  const int wm   = wave & 1, wn = wave >> 1;
  const int lrow = lane & 15, quad = lane >> 4;

  floatx4 zero = {0.f, 0.f, 0.f, 0.f};
  floatx4 acc[4][4];
#pragma unroll
  for (int a = 0; a < 4; ++a)
#pragma unroll
    for (int b = 0; b < 4; ++b) acc[a][b] = zero;

  const float* gA = A + (size_t)(m0 + r) * lda + half * 16;
  const float* gW = W + (size_t)(n0 + r) * K   + half * 16;
  unsigned short* sA = As + r * 40 + half * 16;
  unsigned short* sB = Bs + r * 40 + half * 16;

  for (int k0 = 0; k0 < K; k0 += 32) {
    float4 a0 = *(const float4*)(gA + k0);
    float4 a1 = *(const float4*)(gA + k0 + 4);
    float4 a2 = *(const float4*)(gA + k0 + 8);
    float4 a3 = *(const float4*)(gA + k0 + 12);
    float4 b0 = *(const float4*)(gW + k0);
    float4 b1 = *(const float4*)(gW + k0 + 4);
    float4 b2 = *(const float4*)(gW + k0 + 8);
    float4 b3 = *(const float4*)(gW + k0 + 12);
    __syncthreads();   // previous iter's frag reads done before LDS overwrite
    st_bf4(sA + 0, a0); st_bf4(sA + 4, a1); st_bf4(sA + 8, a2); st_bf4(sA + 12, a3);
    st_bf4(sB + 0, b0); st_bf4(sB + 4, b1); st_bf4(sB + 8, b2); st_bf4(sB + 12, b3);
    __syncthreads();

    short8 af[4], bf_[4];
#pragma unroll
    for (int mi = 0; mi < 4; ++mi)
      af[mi] = *(const short8*)&As[(wm * 64 + mi * 16 + lrow) * 40 + quad * 8];
#pragma unroll
    for (int ni = 0; ni < 4; ++ni)
      bf_[ni] = *(const short8*)&Bs[(wn * 64 + ni * 16 + lrow) * 40 + quad * 8];
#pragma unroll
    for (int mi = 0; mi < 4; ++mi)
#pragma unroll
      for (int ni = 0; ni < 4; ++ni)
        acc[mi][ni] = __builtin_amdgcn_mfma_f32_16x16x32_bf16(af[mi], bf_[ni], acc[mi][ni], 0, 0, 0);
  }

#pragma unroll
  for (int mi = 0; mi < 4; ++mi)
#pragma unroll
    for (int ni = 0; ni < 4; ++ni)
#pragma unroll
      for (int reg = 0; reg < 4; ++reg) {
        int row = m0 + wm * 64 + mi * 16 + quad * 4 + reg;
        int col = n0 + wn * 64 + ni * 16 + lrow;
        float v = acc[mi][ni][reg];
        if (EPI == 1) {
          v += aux[col];
          v = (v > 20.f) ? v : log1pf(__expf(v));
        } else if (EPI == 2) {
          v += aux[(size_t)row * ldc + col];
        }
        C[(size_t)row * ldc + col] = v;
      }
}

// ---------------------------------------------------------------------------
// RMSNorm: one block per row of D=2048
// ---------------------------------------------------------------------------
__global__ void __launch_bounds__(256) rmsnorm_kernel(
    const float* __restrict__ x, const float* __restrict__ w,
    float* __restrict__ out)
{
  const int row = blockIdx.x;
  const float* xr = x + (size_t)row * DMODEL;
  float ss = 0.f;
#pragma unroll
  for (int c = threadIdx.x * 4; c < DMODEL; c += 256 * 4) {
    float4 v = *(const float4*)(xr + c);
    ss += v.x * v.x + v.y * v.y + v.z * v.z + v.w * v.w;
  }
#pragma unroll
  for (int off = 32; off > 0; off >>= 1) ss += __shfl_down(ss, off);
  __shared__ float red[5];
  const int lane = threadIdx.x & 63, wv = threadIdx.x >> 6;
  if (lane == 0) red[wv] = ss;
  __syncthreads();
  if (threadIdx.x == 0)
    red[4] = rsqrtf((red[0] + red[1] + red[2] + red[3]) / (float)DMODEL + 1e-5f);
  __syncthreads();
  const float scale = red[4];
  float* orow = out + (size_t)row * DMODEL;
#pragma unroll
  for (int c = threadIdx.x * 4; c < DMODEL; c += 256 * 4) {
    float4 v  = *(const float4*)(xr + c);
    float4 wv4 = *(const float4*)(w + c);
    float4 o;
    o.x = v.x * scale * wv4.x; o.y = v.y * scale * wv4.y;
    o.z = v.z * scale * wv4.z; o.w = v.w * scale * wv4.w;
    *(float4*)(orow + c) = o;
  }
}

// ---------------------------------------------------------------------------
// Selective scan: 4 lanes per channel, 4 states per lane, sequential over L.
// Fuses D_skip add and silu(z) gating. y written fp32 (1024 x 4096).
// ---------------------------------------------------------------------------
__global__ void __launch_bounds__(256) scan_kernel(
    const float* __restrict__ zx,       // 1024 x ZROW
    const float* __restrict__ dt,       // 1024 x 4096  (post-softplus)
    const float* __restrict__ A_log,    // 4096 x 16
    const float* __restrict__ D_skip,   // 4096
    float* __restrict__ y)              // 1024 x 4096
{
  const int gt = blockIdx.x * 256 + threadIdx.x;   // 0..16383
  const int i  = gt >> 2;                          // channel 0..4095
  const int q  = gt & 3;                           // state quartet
  const int xcol = DINNER + ((i >> 6) << 4) + (i & 15);
  const int bcol = DINNER + DXB + ((i >> 6) << 4) + 4 * q;
  const int ccol = DINNER + 2 * DXB + (i & ~15) + 4 * q;

  float4 al = *(const float4*)(A_log + i * DSTATE + 4 * q);
  const float a0 = -__expf(al.x), a1 = -__expf(al.y);
  const float a2 = -__expf(al.z), a3 = -__expf(al.w);
  const float dsk = D_skip[i];

  float h0 = 0.f, h1 = 0.f, h2 = 0.f, h3 = 0.f;

  float  dt_c = dt[i];
  float  x_c  = zx[xcol];
  float  z_c  = zx[i];
  float4 B_c  = *(const float4*)(zx + bcol);
  float4 C_c  = *(const float4*)(zx + ccol);

  for (int l = 0; l < L_SEQ; ++l) {
    float dt_n = 0.f, x_n = 0.f, z_n = 0.f;
    float4 B_n = B_c, C_n = C_c;
    if (l < L_SEQ - 1) {
      const float* zn = zx + (size_t)(l + 1) * ZROW;
      dt_n = dt[(size_t)(l + 1) * DINNER + i];
      x_n  = zn[xcol];
      z_n  = zn[i];
      B_n  = *(const float4*)(zn + bcol);
      C_n  = *(const float4*)(zn + ccol);
    }
    const float dtx = dt_c * x_c;
    h0 = __expf(dt_c * a0) * h0 + dtx * B_c.x;
    h1 = __expf(dt_c * a1) * h1 + dtx * B_c.y;
    h2 = __expf(dt_c * a2) * h2 + dtx * B_c.z;
    h3 = __expf(dt_c * a3) * h3 + dtx * B_c.w;
    float p = C_c.x * h0 + C_c.y * h1 + C_c.z * h2 + C_c.w * h3;
    p += __shfl_xor(p, 1);
    p += __shfl_xor(p, 2);
    if (q == 0) {
      const float sz = z_c / (1.f + __expf(-z_c));
      y[(size_t)l * DINNER + i] = (p + dsk * x_c) * sz;
    }
    dt_c = dt_n; x_c = x_n; z_c = z_n; B_c = B_n; C_c = C_n;
  }
}

// ---------------------------------------------------------------------------
// hm = silu(gate) * up, fp32, float4-vectorized
// ---------------------------------------------------------------------------
__global__ void __launch_bounds__(256) silu_mul_kernel(
    const float* __restrict__ g, const float* __restrict__ u,
    float* __restrict__ out, int n4)
{
  const int idx = blockIdx.x * 256 + threadIdx.x;
  if (idx < n4) {
    float4 gv = ((const float4*)g)[idx];
    float4 uv = ((const float4*)u)[idx];
    float4 o;
    o.x = gv.x / (1.f + __expf(-gv.x)) * uv.x;
    o.y = gv.y / (1.f + __expf(-gv.y)) * uv.y;
    o.z = gv.z / (1.f + __expf(-gv.z)) * uv.z;
    o.w = gv.w / (1.f + __expf(-gv.w)) * uv.w;
    ((float4*)out)[idx] = o;
  }
}

// ---------------------------------------------------------------------------
extern "C" void kernel_launch(void* const* d_in, const int* in_sizes, int n_in,
                              void* d_out, int out_size, void* d_ws, size_t ws_size,
                              hipStream_t stream)
{
  const float* hidden    = (const float*)d_in[0];
  const float* rms1_w    = (const float*)d_in[1];
  const float* in_proj_w = (const float*)d_in[2];
  const float* dt_proj_w = (const float*)d_in[3];
  const float* dt_proj_b = (const float*)d_in[4];
  const float* A_log     = (const float*)d_in[5];
  const float* D_skip    = (const float*)d_in[6];
  const float* out_proj_w= (const float*)d_in[7];
  const float* rms2_w    = (const float*)d_in[8];
  const float* gate_w    = (const float*)d_in[9];
  const float* up_w      = (const float*)d_in[10];
  const float* down_w    = (const float*)d_in[11];
  float* out = (float*)d_out;

  char* ws = (char*)d_ws;
  // workspace layout (bytes)
  float* h_norm = (float*)(ws + 0);                        //  8,388,608
  float* zxbcdt = (float*)(ws + 8388608);                  // 42,467,328
  float* dtbuf  = (float*)(ws + 50855936);                 // 16,777,216
  float* ybuf   = (float*)(ws + 67633152);                 // 16,777,216
  float* h2     = (float*)(ws + 84410368);                 //  8,388,608
  float* hn     = (float*)(ws + 92798976);                 //  8,388,608
  float* upb    = (float*)(ws + 101187584);                // 33,554,432 -> 134,742,016 total
  float* gateb  = zxbcdt;                                  // alias (dead after scan)
  float* hmb    = dtbuf;                                   // alias dt+y span (dead after out_proj)

  // 1) rmsnorm1
  rmsnorm_kernel<<<L_SEQ, 256, 0, stream>>>(hidden, rms1_w, h_norm);
  // 2) zxbcdt = h_norm @ in_proj_w.T      (1024 x 10368, K=2048)
  gemm_bt<0><<<dim3(ZROW / 128, L_SEQ / 128), 256, 0, stream>>>(
      h_norm, DMODEL, in_proj_w, zxbcdt, ZROW, DMODEL, nullptr);
  // 3) dt = softplus(dt_in @ dt_proj_w.T + b)   (1024 x 4096, K=128)
  gemm_bt<1><<<dim3(DINNER / 128, L_SEQ / 128), 256, 0, stream>>>(
      zxbcdt + 2 * DINNER + 2 * DXB, ZROW, dt_proj_w, dtbuf, DINNER, DTRANK, dt_proj_b);
  // 4) selective scan + gating -> ybuf
  scan_kernel<<<64, 256, 0, stream>>>(zxbcdt, dtbuf, A_log, D_skip, ybuf);
  // 5) h2 = hidden + ybuf @ out_proj_w.T  (1024 x 2048, K=4096)
  gemm_bt<2><<<dim3(DMODEL / 128, L_SEQ / 128), 256, 0, stream>>>(
      ybuf, DINNER, out_proj_w, h2, DMODEL, DINNER, hidden);
  // 6) rmsnorm2
  rmsnorm_kernel<<<L_SEQ, 256, 0, stream>>>(h2, rms2_w, hn);
  // 7) gate = hn @ gate_w.T ; up = hn @ up_w.T   (1024 x 8192, K=2048)
  gemm_bt<0><<<dim3(INTER / 128, L_SEQ / 128), 256, 0, stream>>>(
      hn, DMODEL, gate_w, gateb, INTER, DMODEL, nullptr);
  gemm_bt<0><<<dim3(INTER / 128, L_SEQ / 128), 256, 0, stream>>>(
      hn, DMODEL, up_w, upb, INTER, DMODEL, nullptr);
  // 8) hm = silu(gate) * up
  silu_mul_kernel<<<(L_SEQ * INTER / 4) / 256, 256, 0, stream>>>(
      gateb, upb, hmb, L_SEQ * INTER / 4);
  // 9) out = h2 + hm @ down_w.T           (1024 x 2048, K=8192)
  gemm_bt<2><<<dim3(DMODEL / 128, L_SEQ / 128), 256, 0, stream>>>(
      hmb, INTER, down_w, out, DMODEL, INTER, h2);
}